// Round 6
// baseline (250.691 us; speedup 1.0000x reference)
//
#include <hip/hip_runtime.h>
#include <hip/hip_bf16.h>
#include <math.h>

typedef unsigned short u16;
typedef unsigned int   u32;
using bf16x8 = __attribute__((ext_vector_type(8))) short;   // 8 bf16 (4 VGPRs)
using f32x4  = __attribute__((ext_vector_type(4))) float;   // MFMA C/D frag

#define TE 256
#define TH 8
#define TS 2048
#define TB 4
#define NTOK 8192
// (1/sqrt(32)) * log2(e): folded into Q so softmax is pure exp2
#define QSCALE 0.2550120651552454f
#define EXP2(x) __builtin_amdgcn_exp2f(x)

// pack 2 floats -> 2 bf16 (round-half-up): 2 adds + v_perm
__device__ __forceinline__ u32 pkbf(float a, float b) {
    u32 ua = __float_as_uint(a) + 0x8000u;
    u32 ub = __float_as_uint(b) + 0x8000u;
    return __builtin_amdgcn_perm(ub, ua, 0x07060302u);
}

// ---------------- LayerNorm: one wave per row, bf16 output -----------------
__global__ __launch_bounds__(256) void ln_bf(const float* __restrict__ in,
        u16* __restrict__ out, const float* __restrict__ gamma,
        const float* __restrict__ beta) {
    int row  = blockIdx.x * 4 + (threadIdx.x >> 6);
    int lane = threadIdx.x & 63;
    float4 v = ((const float4*)(in + (size_t)row * TE))[lane];
    float s  = v.x + v.y + v.z + v.w;
    float s2 = v.x*v.x + v.y*v.y + v.z*v.z + v.w*v.w;
    #pragma unroll
    for (int off = 32; off > 0; off >>= 1) {
        s  += __shfl_down(s,  off, 64);
        s2 += __shfl_down(s2, off, 64);
    }
    s  = __shfl(s,  0, 64);
    s2 = __shfl(s2, 0, 64);
    float mu = s * (1.f / TE);
    float rs = rsqrtf(s2 * (1.f / TE) - mu * mu + 1e-5f);
    float4 g = ((const float4*)gamma)[lane];
    float4 b = ((const float4*)beta )[lane];
    u32 lo = pkbf((v.x - mu) * rs * g.x + b.x, (v.y - mu) * rs * g.y + b.y);
    u32 hi = pkbf((v.z - mu) * rs * g.z + b.z, (v.w - mu) * rs * g.w + b.w);
    ((uint2*)(out + (size_t)row * TE))[lane] = make_uint2(lo, hi);
}

// -------------- convert the 4 weight matrices fp32 -> bf16 -----------------
__global__ __launch_bounds__(256) void convw(const float* __restrict__ s0, u16* d0,
        const float* __restrict__ s1, u16* d1, const float* __restrict__ s2, u16* d2,
        const float* __restrict__ s3, u16* d3) {
    int i = (blockIdx.x * 256 + threadIdx.x) * 4;
    const float* s; u16* d;
    if      (i < 196608) { s = s0; d = d0; }
    else if (i < 262144) { s = s1; d = d1; i -= 196608; }
    else if (i < 524288) { s = s2; d = d2; i -= 262144; }
    else                 { s = s3; d = d3; i -= 524288; }
    float4 v = *(const float4*)(s + i);
    *(uint2*)(d + i) = make_uint2(pkbf(v.x, v.y), pkbf(v.z, v.w));
}

// ---------- weight-stationary GEMM: C[tok][feat] = A[tok][K] @ W^T ---------
// Block = 4 waves sharing one W feat-slice in LDS (staged ONCE -> exactly one
// barrier; K-loop is barrier-free so waves pipeline independently).
// A frags load DIRECTLY from global in B-operand layout (lane fr = token,
// fq*8.. = k contiguous). D = mfma(wf, af): rows = feat, cols = tok -> lane
// holds 4 consecutive feats of one token -> vector stores.
// EPI: 0 = bf16 +qscale(feat<256); 1 = fp32 + residual R;
//      2 = bf16 relu(acc+bias); 3 = fp32 atomicAdd(+bias if koff==0)  [K-split].
template<int K, int Kc, int NFEAT, int NF, int EPI>
__global__ __launch_bounds__(256) void wgemm(const u16* __restrict__ A,
        const u16* __restrict__ W, const float* __restrict__ bias,
        const float* __restrict__ R, float* __restrict__ Cf,
        u16* __restrict__ Cb, int M) {
    constexpr int LROW = Kc + 8;                 // +16B pad: row stride 4 banks
    __shared__ u16 Wl[NFEAT * LROW];
    const int tid = threadIdx.x, w = tid >> 6, l = tid & 63;
    const int fr = l & 15, fq = l >> 4;
    int slice, koff;
    if (EPI == 3) { slice = blockIdx.x >> 1; koff = (blockIdx.x & 1) * Kc; }
    else          { slice = blockIdx.x;      koff = 0; }
    const int fbase = slice * NFEAT;
    const int tok0 = blockIdx.y * 256 + w * 64;

    // stage W[fbase..+NFEAT][koff..+Kc] into padded LDS (one time)
    {
        constexpr int CH = NFEAT * Kc / 8;       // 16B chunks
        #pragma unroll
        for (int c0 = 0; c0 < CH; c0 += 256) {
            int c = c0 + tid;
            int row = c / (Kc / 8), cp = c % (Kc / 8);
            *(uint4*)&Wl[row * LROW + cp * 8] =
                *(const uint4*)(W + (size_t)(fbase + row) * K + koff + cp * 8);
        }
    }
    __syncthreads();

    f32x4 acc[4][NF];
    #pragma unroll
    for (int t = 0; t < 4; t++)
        #pragma unroll
        for (int f = 0; f < NF; f++)
            #pragma unroll
            for (int r = 0; r < 4; r++) acc[t][f][r] = 0.f;

    const u16* arow0 = A + (size_t)(tok0 + fr) * K + koff;
    constexpr int STEPS = Kc / 32;
    #pragma unroll 4
    for (int s = 0; s < STEPS; s++) {
        bf16x8 af[4], wf[NF];
        #pragma unroll
        for (int t = 0; t < 4; t++)
            af[t] = *(const bf16x8*)(arow0 + (size_t)t * 16 * K + s * 32 + fq * 8);
        #pragma unroll
        for (int f = 0; f < NF; f++)
            wf[f] = *(const bf16x8*)&Wl[(f * 16 + fr) * LROW + s * 32 + fq * 8];
        #pragma unroll
        for (int t = 0; t < 4; t++)
            #pragma unroll
            for (int f = 0; f < NF; f++)
                acc[t][f] = __builtin_amdgcn_mfma_f32_16x16x32_bf16(
                    wf[f], af[t], acc[t][f], 0, 0, 0);
    }

    #pragma unroll
    for (int t = 0; t < 4; t++) {
        const int tok = tok0 + t * 16 + fr;
        #pragma unroll
        for (int f = 0; f < NF; f++) {
            const int fb = fbase + f * 16 + fq * 4;
            f32x4 v = acc[t][f];
            if (EPI == 0) {
                const float qs = (fb < 256) ? QSCALE : 1.f;
                *(uint2*)(Cb + (size_t)tok * M + fb) =
                    make_uint2(pkbf(v[0]*qs, v[1]*qs), pkbf(v[2]*qs, v[3]*qs));
            } else if (EPI == 1) {
                float4 r4 = *(const float4*)(R + (size_t)tok * M + fb);
                *(float4*)(Cf + (size_t)tok * M + fb) =
                    make_float4(v[0]+r4.x, v[1]+r4.y, v[2]+r4.z, v[3]+r4.w);
            } else if (EPI == 2) {
                float4 b4 = *(const float4*)(bias + fb);
                *(uint2*)(Cb + (size_t)tok * M + fb) = make_uint2(
                    pkbf(fmaxf(v[0]+b4.x, 0.f), fmaxf(v[1]+b4.y, 0.f)),
                    pkbf(fmaxf(v[2]+b4.z, 0.f), fmaxf(v[3]+b4.w, 0.f)));
            } else {
                float bb[4] = {0.f, 0.f, 0.f, 0.f};
                if (koff == 0) {
                    float4 b4 = *(const float4*)(bias + fb);
                    bb[0] = b4.x; bb[1] = b4.y; bb[2] = b4.z; bb[3] = b4.w;
                }
                float* cp_ = Cf + (size_t)tok * M + fb;
                #pragma unroll
                for (int r = 0; r < 4; r++) atomicAdd(cp_ + r, v[r] + bb[r]);
            }
        }
    }
}

// ---- MFMA flash attention: no-max softmax, kv-split, software-pipelined ---
// Block = (b,h) x 64 q. qw=w&1 picks 32-q group, kw=w>>1 picks kv half.
// 2-stage pipeline: kf prefetched 2 subs ahead; QK MFMA for sub+1 issued
// between P-store and PV of sub (exp2 input always 1 sub old -> MFMA latency
// hidden; P LDS round-trip overlaps QK issue).
__global__ __launch_bounds__(256) void attn_k(const u16* __restrict__ qkv,
        u16* __restrict__ attn) {
    const int bh = blockIdx.x, b = bh >> 3, h = bh & 7;
    const int q0 = blockIdx.y * 64;
    const int tid = threadIdx.x, w = tid >> 6, l = tid & 63;
    const int qw = w & 1, kw = w >> 1;
    const int fr = l & 15, fq = l >> 4;
    const size_t btok = (size_t)b * TS;

    __shared__ u16 Vt[2][4 * 1296];   // per kv-half: 4 chunks [32 d][40 kv+pad]
    __shared__ u16 Pl[4][32 * 40];    // per-wave P: [32 q][40]

    bf16x8 qf[2];                     // B-operand: fr = q, fq*8.. = d
    #pragma unroll
    for (int qs = 0; qs < 2; qs++)
        qf[qs] = *(const bf16x8*)(qkv +
            (btok + q0 + qw * 32 + qs * 16 + fr) * 768 + h * 32 + fq * 8);

    f32x4 o[2][2];                    // O^T: (d = ds*16+fq*4+r, q = qs*16+fr)
    #pragma unroll
    for (int ds = 0; ds < 2; ds++)
        #pragma unroll
        for (int qs = 0; qs < 2; qs++)
            #pragma unroll
            for (int r = 0; r < 4; r++) o[ds][qs][r] = 0.f;
    float ps[2] = {0.f, 0.f};

    u16* Pw = Pl[w];
    const int vkv = l * 2, vd0 = qw * 16;
    const u16* kbase = qkv + btok * 768 + 256 + h * 32;
    const int kvbase = kw * 1024;

#define KLOAD(ci, a_, b_) { \
        const u16* krow_ = kbase + (size_t)(kvbase + (ci) * 32) * 768; \
        a_ = *(const bf16x8*)(krow_ + (size_t)fr * 768 + fq * 8); \
        b_ = *(const bf16x8*)(krow_ + (size_t)(16 + fr) * 768 + fq * 8); }

    bf16x8 kA[2], kB[2];
    f32x4 st[2][2][2];                // [parity][kv-half-of-32][qs]
    KLOAD(0, kA[0], kB[0]);
    KLOAD(1, kA[1], kB[1]);
    {
        f32x4 z; z[0] = z[1] = z[2] = z[3] = 0.f;
        #pragma unroll
        for (int qs = 0; qs < 2; qs++) {
            st[0][0][qs] = __builtin_amdgcn_mfma_f32_16x16x32_bf16(kA[0], qf[qs], z, 0, 0, 0);
            st[0][1][qs] = __builtin_amdgcn_mfma_f32_16x16x32_bf16(kB[0], qf[qs], z, 0, 0, 0);
        }
    }

    for (int it = 0; it < 8; it++) {
        const int kv0 = kvbase + it * 128;
        __syncthreads();              // Vt reuse fence
        {   // stage V^T for this wave-pair's kv half: 2 kv rows x 16 d / thread
            const u16* va = qkv + (btok + kv0 + vkv) * 768 + 512 + h * 32 + vd0;
            uint4 ra0 = *(const uint4*)va;
            uint4 ra1 = *(const uint4*)(va + 8);
            uint4 rb0 = *(const uint4*)(va + 768);
            uint4 rb1 = *(const uint4*)(va + 776);
            const u16* pa0 = (const u16*)&ra0; const u16* pa1 = (const u16*)&ra1;
            const u16* pb0 = (const u16*)&rb0; const u16* pb1 = (const u16*)&rb1;
            u16* vb_ = &Vt[kw][(vkv >> 5) * 1296 + (vkv & 31)];
            #pragma unroll
            for (int i = 0; i < 8; i++) {
                *(u32*)&vb_[(vd0 + i) * 40]     = (u32)pa0[i] | ((u32)pb0[i] << 16);
                *(u32*)&vb_[(vd0 + 8 + i) * 40] = (u32)pa1[i] | ((u32)pb1[i] << 16);
            }
        }
        __syncthreads();
        #pragma unroll
        for (int sub = 0; sub < 4; sub++) {
            const int ci = it * 4 + sub;
            const int p = ci & 1, np = p ^ 1;
            // 1. prefetch kf for ci+2 into the just-freed slot
            KLOAD((ci + 2) & 31, kA[p], kB[p]);
            // 2. exp/pack/store P for current st[p]
            #pragma unroll
            for (int qs = 0; qs < 2; qs++) {
                float p0[4], p1[4];
                #pragma unroll
                for (int r = 0; r < 4; r++) {
                    p0[r] = EXP2(st[p][0][qs][r]);
                    p1[r] = EXP2(st[p][1][qs][r]);
                }
                ps[qs] += ((p0[0]+p0[1]) + (p0[2]+p0[3]))
                        + ((p1[0]+p1[1]) + (p1[2]+p1[3]));
                u16* prow = &Pw[(qs * 16 + fr) * 40];
                *(uint2*)&prow[fq * 4]      = make_uint2(pkbf(p0[0],p0[1]), pkbf(p0[2],p0[3]));
                *(uint2*)&prow[16 + fq * 4] = make_uint2(pkbf(p1[0],p1[1]), pkbf(p1[2],p1[3]));
            }
            // 3. QK for ci+1 (MFMA issue overlaps P-write latency)
            {
                f32x4 z; z[0] = z[1] = z[2] = z[3] = 0.f;
                #pragma unroll
                for (int qs = 0; qs < 2; qs++) {
                    st[np][0][qs] = __builtin_amdgcn_mfma_f32_16x16x32_bf16(kA[np], qf[qs], z, 0, 0, 0);
                    st[np][1][qs] = __builtin_amdgcn_mfma_f32_16x16x32_bf16(kB[np], qf[qs], z, 0, 0, 0);
                }
            }
            // 4. PV: O^T += V^T * P^T
            bf16x8 pf0 = *(const bf16x8*)&Pw[fr * 40 + fq * 8];
            bf16x8 pf1 = *(const bf16x8*)&Pw[(16 + fr) * 40 + fq * 8];
            bf16x8 vf0 = *(const bf16x8*)&Vt[kw][sub * 1296 + fr * 40 + fq * 8];
            bf16x8 vf1 = *(const bf16x8*)&Vt[kw][sub * 1296 + (16 + fr) * 40 + fq * 8];
            o[0][0] = __builtin_amdgcn_mfma_f32_16x16x32_bf16(vf0, pf0, o[0][0], 0, 0, 0);
            o[0][1] = __builtin_amdgcn_mfma_f32_16x16x32_bf16(vf0, pf1, o[0][1], 0, 0, 0);
            o[1][0] = __builtin_amdgcn_mfma_f32_16x16x32_bf16(vf1, pf0, o[1][0], 0, 0, 0);
            o[1][1] = __builtin_amdgcn_mfma_f32_16x16x32_bf16(vf1, pf1, o[1][1], 0, 0, 0);
        }
    }
    // reduce ps across fq within each wave
    #pragma unroll
    for (int qs = 0; qs < 2; qs++) {
        ps[qs] += __shfl_xor(ps[qs], 16, 64);
        ps[qs] += __shfl_xor(ps[qs], 32, 64);
    }
    // merge kv halves: kw=1 dumps (o, ps); kw=0 adds + stores
    __syncthreads();
    float* mrg = (float*)&Vt[0][0];   // 128 lanes x 18 floats = 9216 B
    if (kw == 1) {
        float* p = mrg + (qw * 64 + l) * 18;
        #pragma unroll
        for (int ds = 0; ds < 2; ds++)
            #pragma unroll
            for (int qs = 0; qs < 2; qs++)
                #pragma unroll
                for (int r = 0; r < 4; r++) p[ds * 8 + qs * 4 + r] = o[ds][qs][r];
        p[16] = ps[0]; p[17] = ps[1];
    }
    __syncthreads();
    if (kw == 0) {
        const float* p = mrg + (qw * 64 + l) * 18;
        #pragma unroll
        for (int ds = 0; ds < 2; ds++)
            #pragma unroll
            for (int qs = 0; qs < 2; qs++)
                #pragma unroll
                for (int r = 0; r < 4; r++) o[ds][qs][r] += p[ds * 8 + qs * 4 + r];
        ps[0] += p[16]; ps[1] += p[17];
        #pragma unroll
        for (int qs = 0; qs < 2; qs++) {
            float inv = 1.f / ps[qs];
            int tok = (int)btok + q0 + qw * 32 + qs * 16 + fr;
            #pragma unroll
            for (int ds = 0; ds < 2; ds++) {
                *(uint2*)(attn + (size_t)tok * 256 + h * 32 + ds * 16 + fq * 4) =
                    make_uint2(pkbf(o[ds][qs][0]*inv, o[ds][qs][1]*inv),
                               pkbf(o[ds][qs][2]*inv, o[ds][qs][3]*inv));
            }
        }
    }
#undef KLOAD
}

extern "C" void kernel_launch(void* const* d_in, const int* in_sizes, int n_in,
                              void* d_out, int out_size, void* d_ws, size_t ws_size,
                              hipStream_t stream) {
    const float* src  = (const float*)d_in[0];
    const float* w_in = (const float*)d_in[1];
    const float* w_out= (const float*)d_in[2];
    const float* w1   = (const float*)d_in[3];
    const float* b1   = (const float*)d_in[4];
    const float* w2   = (const float*)d_in[5];
    const float* b2   = (const float*)d_in[6];
    const float* g1   = (const float*)d_in[7];
    const float* be1  = (const float*)d_in[8];
    const float* g2   = (const float*)d_in[9];
    const float* be2  = (const float*)d_in[10];
    float* out = (float*)d_out;

    u16* xb    = (u16*)d_ws;                       // 8192*256
    u16* qkvb  = xb + (size_t)NTOK * 256;          // 8192*768
    u16* attnb = xb;                               // reuse (xb dead after G2)
    u16* h1b   = (u16*)d_ws;                       // 8192*1024 (after attn GEMMs)
    u16* x2b   = (u16*)((char*)d_ws + (size_t)NTOK * 1024 * 2);
    u16* wib   = x2b + (size_t)NTOK * 256;
    u16* wob   = wib + 768 * 256;
    u16* w1b   = wob + 256 * 256;
    u16* w2b   = w1b + 1024 * 256;

    convw<<<768, 256, 0, stream>>>(w_in, wib, w_out, wob, w1, w1b, w2, w2b);
    // 1. xb = LN1(src) -> bf16
    ln_bf<<<NTOK / 4, 256, 0, stream>>>(src, xb, g1, be1);
    // 2. qkvb = xb @ w_in^T (q cols scaled by QSCALE*log2e)
    wgemm<256, 256, 64, 4, 0><<<dim3(12, 32), 256, 0, stream>>>(
        xb, wib, nullptr, nullptr, nullptr, qkvb, 768);
    // 3. attnb = flash-attention(qkvb)
    attn_k<<<dim3(32, 32), 256, 0, stream>>>(qkvb, attnb);
    // 4. out = src + attnb @ w_out^T (fp32)
    wgemm<256, 256, 32, 2, 1><<<dim3(8, 32), 256, 0, stream>>>(
        attnb, wob, nullptr, src, out, nullptr, 256);
    // 5. x2b = LN2(out) -> bf16
    ln_bf<<<NTOK / 4, 256, 0, stream>>>(out, x2b, g2, be2);
    // 6. h1b = relu(x2b @ w1^T + b1) -> bf16
    wgemm<256, 256, 64, 4, 2><<<dim3(16, 32), 256, 0, stream>>>(
        x2b, w1b, b1, nullptr, nullptr, h1b, 1024);
    // 7. out += h1b @ w2^T + b2 (K-split-2, fp32 atomic merge)
    wgemm<1024, 512, 32, 2, 3><<<dim3(16, 32), 256, 0, stream>>>(
        h1b, w2b, b2, nullptr, out, nullptr, 256);
}

// Round 7
// 204.720 us; speedup vs baseline: 1.2246x; 1.2246x over previous
//
#include <hip/hip_runtime.h>
#include <hip/hip_bf16.h>
#include <math.h>

typedef unsigned short u16;
typedef unsigned int   u32;
using bf16x8 = __attribute__((ext_vector_type(8))) short;   // 8 bf16 (4 VGPRs)
using f32x4  = __attribute__((ext_vector_type(4))) float;   // MFMA C/D frag

#define TE 256
#define TH 8
#define TS 2048
#define TB 4
#define NTOK 8192
// (1/sqrt(32)) * log2(e): folded into Q so softmax is pure exp2
#define QSCALE 0.2550120651552454f
#define EXP2(x) __builtin_amdgcn_exp2f(x)

// pack 2 floats -> 2 bf16 (round-half-up): 2 adds + v_perm
__device__ __forceinline__ u32 pkbf(float a, float b) {
    u32 ua = __float_as_uint(a) + 0x8000u;
    u32 ub = __float_as_uint(b) + 0x8000u;
    return __builtin_amdgcn_perm(ub, ua, 0x07060302u);
}

// ---------------- LayerNorm: one wave per row, bf16 output -----------------
__global__ __launch_bounds__(256) void ln_bf(const float* __restrict__ in,
        u16* __restrict__ out, const float* __restrict__ gamma,
        const float* __restrict__ beta) {
    int row  = blockIdx.x * 4 + (threadIdx.x >> 6);
    int lane = threadIdx.x & 63;
    float4 v = ((const float4*)(in + (size_t)row * TE))[lane];
    float s  = v.x + v.y + v.z + v.w;
    float s2 = v.x*v.x + v.y*v.y + v.z*v.z + v.w*v.w;
    #pragma unroll
    for (int off = 32; off > 0; off >>= 1) {
        s  += __shfl_down(s,  off, 64);
        s2 += __shfl_down(s2, off, 64);
    }
    s  = __shfl(s,  0, 64);
    s2 = __shfl(s2, 0, 64);
    float mu = s * (1.f / TE);
    float rs = rsqrtf(s2 * (1.f / TE) - mu * mu + 1e-5f);
    float4 g = ((const float4*)gamma)[lane];
    float4 b = ((const float4*)beta )[lane];
    u32 lo = pkbf((v.x - mu) * rs * g.x + b.x, (v.y - mu) * rs * g.y + b.y);
    u32 hi = pkbf((v.z - mu) * rs * g.z + b.z, (v.w - mu) * rs * g.w + b.w);
    ((uint2*)(out + (size_t)row * TE))[lane] = make_uint2(lo, hi);
}

// -------------- convert the 4 weight matrices fp32 -> bf16 -----------------
__global__ __launch_bounds__(256) void convw(const float* __restrict__ s0, u16* d0,
        const float* __restrict__ s1, u16* d1, const float* __restrict__ s2, u16* d2,
        const float* __restrict__ s3, u16* d3) {
    int i = (blockIdx.x * 256 + threadIdx.x) * 4;
    const float* s; u16* d;
    if      (i < 196608) { s = s0; d = d0; }
    else if (i < 262144) { s = s1; d = d1; i -= 196608; }
    else if (i < 524288) { s = s2; d = d2; i -= 262144; }
    else                 { s = s3; d = d3; i -= 524288; }
    float4 v = *(const float4*)(s + i);
    *(uint2*)(d + i) = make_uint2(pkbf(v.x, v.y), pkbf(v.z, v.w));
}

// ---------- weight-stationary GEMM: C[tok][feat] = A[tok][K] @ W^T ---------
// Block = 4 waves sharing one W feat-slice in LDS, staged in <=512-k chunks
// (1 chunk for K=256, 2 for K=1024 -> 1 or 3 barriers/block; K-loop itself is
// barrier-free so waves pipeline independently). A frags load DIRECTLY from
// global in B-operand layout (lane fr = token, fq*8.. = k). D = mfma(wf, af):
// rows = feat, cols = tok -> lane holds 4 consecutive feats -> vector stores.
// Wave covers 32 tokens (NT=2): 128 tok/block for occupancy (grid 512-1024).
// LDS row pad +8 u16: row stride/16B = odd -> 16-lane b128 phases hit 2-way
// bank aliasing only (free).
// EPI: 0 = bf16 +qscale(feat<256); 1 = fp32 + residual R;
//      2 = bf16 relu(acc+bias); 3 = fp32 acc + bias + Cf (in-place residual).
template<int K, int NFEAT, int NF, int EPI>
__global__ __launch_bounds__(256) void wgemm(const u16* __restrict__ A,
        const u16* __restrict__ W, const float* __restrict__ bias,
        const float* __restrict__ R, float* __restrict__ Cf,
        u16* __restrict__ Cb, int M) {
    constexpr int KC = (K < 512) ? K : 512;      // W chunk along k
    constexpr int LROW = KC + 8;
    __shared__ u16 Wl[NFEAT * LROW];
    const int tid = threadIdx.x, w = tid >> 6, l = tid & 63;
    const int fr = l & 15, fq = l >> 4;
    const int fbase = blockIdx.x * NFEAT;
    const int tok0 = blockIdx.y * 128 + w * 32;

    f32x4 acc[2][NF];
    #pragma unroll
    for (int t = 0; t < 2; t++)
        #pragma unroll
        for (int f = 0; f < NF; f++)
            #pragma unroll
            for (int r = 0; r < 4; r++) acc[t][f][r] = 0.f;

    const u16* arow0 = A + (size_t)(tok0 + fr) * K;

    for (int kc = 0; kc < K; kc += KC) {
        if (kc) __syncthreads();                 // previous chunk's reads done
        {   // stage W[fbase..+NFEAT][kc..kc+KC] into padded LDS
            constexpr int CH = NFEAT * KC / 8;   // 16B chunks (multiple of 256)
            #pragma unroll
            for (int c0 = 0; c0 < CH; c0 += 256) {
                int c = c0 + tid;
                int row = c / (KC / 8), cp = c % (KC / 8);
                *(uint4*)&Wl[row * LROW + cp * 8] =
                    *(const uint4*)(W + (size_t)(fbase + row) * K + kc + cp * 8);
            }
        }
        __syncthreads();
        constexpr int STEPS = KC / 32;
        #pragma unroll 4
        for (int s = 0; s < STEPS; s++) {
            bf16x8 af[2], wf[NF];
            #pragma unroll
            for (int t = 0; t < 2; t++)
                af[t] = *(const bf16x8*)(arow0 + (size_t)t * 16 * K + kc + s * 32 + fq * 8);
            #pragma unroll
            for (int f = 0; f < NF; f++)
                wf[f] = *(const bf16x8*)&Wl[(f * 16 + fr) * LROW + s * 32 + fq * 8];
            #pragma unroll
            for (int t = 0; t < 2; t++)
                #pragma unroll
                for (int f = 0; f < NF; f++)
                    acc[t][f] = __builtin_amdgcn_mfma_f32_16x16x32_bf16(
                        wf[f], af[t], acc[t][f], 0, 0, 0);
        }
    }

    #pragma unroll
    for (int t = 0; t < 2; t++) {
        const int tok = tok0 + t * 16 + fr;
        #pragma unroll
        for (int f = 0; f < NF; f++) {
            const int fb = fbase + f * 16 + fq * 4;
            f32x4 v = acc[t][f];
            if (EPI == 0) {
                const float qs = (fb < 256) ? QSCALE : 1.f;
                *(uint2*)(Cb + (size_t)tok * M + fb) =
                    make_uint2(pkbf(v[0]*qs, v[1]*qs), pkbf(v[2]*qs, v[3]*qs));
            } else if (EPI == 1) {
                float4 r4 = *(const float4*)(R + (size_t)tok * M + fb);
                *(float4*)(Cf + (size_t)tok * M + fb) =
                    make_float4(v[0]+r4.x, v[1]+r4.y, v[2]+r4.z, v[3]+r4.w);
            } else if (EPI == 2) {
                float4 b4 = *(const float4*)(bias + fb);
                *(uint2*)(Cb + (size_t)tok * M + fb) = make_uint2(
                    pkbf(fmaxf(v[0]+b4.x, 0.f), fmaxf(v[1]+b4.y, 0.f)),
                    pkbf(fmaxf(v[2]+b4.z, 0.f), fmaxf(v[3]+b4.w, 0.f)));
            } else {   // in-place: out = acc + bias + out
                float4 b4 = *(const float4*)(bias + fb);
                float4 r4 = *(const float4*)(Cf + (size_t)tok * M + fb);
                *(float4*)(Cf + (size_t)tok * M + fb) = make_float4(
                    v[0]+b4.x+r4.x, v[1]+b4.y+r4.y, v[2]+b4.z+r4.z, v[3]+b4.w+r4.w);
            }
        }
    }
}

// ---- MFMA flash attention: no-max softmax, kv-split, software-pipelined ---
// Block = (b,h) x 64 q. qw=w&1 picks 32-q group, kw=w>>1 picks kv half.
// 2-stage pipeline: kf prefetched 2 subs ahead; QK MFMA for sub+1 issued
// between P-store and PV of sub (exp2 input always 1 sub old).
__global__ __launch_bounds__(256) void attn_k(const u16* __restrict__ qkv,
        u16* __restrict__ attn) {
    const int bh = blockIdx.x, b = bh >> 3, h = bh & 7;
    const int q0 = blockIdx.y * 64;
    const int tid = threadIdx.x, w = tid >> 6, l = tid & 63;
    const int qw = w & 1, kw = w >> 1;
    const int fr = l & 15, fq = l >> 4;
    const size_t btok = (size_t)b * TS;

    __shared__ u16 Vt[2][4 * 1296];   // per kv-half: 4 chunks [32 d][40 kv+pad]
    __shared__ u16 Pl[4][32 * 40];    // per-wave P: [32 q][40]

    bf16x8 qf[2];                     // B-operand: fr = q, fq*8.. = d
    #pragma unroll
    for (int qs = 0; qs < 2; qs++)
        qf[qs] = *(const bf16x8*)(qkv +
            (btok + q0 + qw * 32 + qs * 16 + fr) * 768 + h * 32 + fq * 8);

    f32x4 o[2][2];                    // O^T: (d = ds*16+fq*4+r, q = qs*16+fr)
    #pragma unroll
    for (int ds = 0; ds < 2; ds++)
        #pragma unroll
        for (int qs = 0; qs < 2; qs++)
            #pragma unroll
            for (int r = 0; r < 4; r++) o[ds][qs][r] = 0.f;
    float ps[2] = {0.f, 0.f};

    u16* Pw = Pl[w];
    const int vkv = l * 2, vd0 = qw * 16;
    const u16* kbase = qkv + btok * 768 + 256 + h * 32;
    const int kvbase = kw * 1024;

#define KLOAD(ci, a_, b_) { \
        const u16* krow_ = kbase + (size_t)(kvbase + (ci) * 32) * 768; \
        a_ = *(const bf16x8*)(krow_ + (size_t)fr * 768 + fq * 8); \
        b_ = *(const bf16x8*)(krow_ + (size_t)(16 + fr) * 768 + fq * 8); }

    bf16x8 kA[2], kB[2];
    f32x4 st[2][2][2];                // [parity][kv-half-of-32][qs]
    KLOAD(0, kA[0], kB[0]);
    KLOAD(1, kA[1], kB[1]);
    {
        f32x4 z; z[0] = z[1] = z[2] = z[3] = 0.f;
        #pragma unroll
        for (int qs = 0; qs < 2; qs++) {
            st[0][0][qs] = __builtin_amdgcn_mfma_f32_16x16x32_bf16(kA[0], qf[qs], z, 0, 0, 0);
            st[0][1][qs] = __builtin_amdgcn_mfma_f32_16x16x32_bf16(kB[0], qf[qs], z, 0, 0, 0);
        }
    }

    for (int it = 0; it < 8; it++) {
        const int kv0 = kvbase + it * 128;
        __syncthreads();              // Vt reuse fence
        {   // stage V^T for this wave-pair's kv half: 2 kv rows x 16 d / thread
            const u16* va = qkv + (btok + kv0 + vkv) * 768 + 512 + h * 32 + vd0;
            uint4 ra0 = *(const uint4*)va;
            uint4 ra1 = *(const uint4*)(va + 8);
            uint4 rb0 = *(const uint4*)(va + 768);
            uint4 rb1 = *(const uint4*)(va + 776);
            const u16* pa0 = (const u16*)&ra0; const u16* pa1 = (const u16*)&ra1;
            const u16* pb0 = (const u16*)&rb0; const u16* pb1 = (const u16*)&rb1;
            u16* vb_ = &Vt[kw][(vkv >> 5) * 1296 + (vkv & 31)];
            #pragma unroll
            for (int i = 0; i < 8; i++) {
                *(u32*)&vb_[(vd0 + i) * 40]     = (u32)pa0[i] | ((u32)pb0[i] << 16);
                *(u32*)&vb_[(vd0 + 8 + i) * 40] = (u32)pa1[i] | ((u32)pb1[i] << 16);
            }
        }
        __syncthreads();
        #pragma unroll
        for (int sub = 0; sub < 4; sub++) {
            const int ci = it * 4 + sub;
            const int p = ci & 1, np = p ^ 1;
            // 1. prefetch kf for ci+2 into the just-freed slot
            KLOAD((ci + 2) & 31, kA[p], kB[p]);
            // 2. exp/pack/store P for current st[p]
            #pragma unroll
            for (int qs = 0; qs < 2; qs++) {
                float p0[4], p1[4];
                #pragma unroll
                for (int r = 0; r < 4; r++) {
                    p0[r] = EXP2(st[p][0][qs][r]);
                    p1[r] = EXP2(st[p][1][qs][r]);
                }
                ps[qs] += ((p0[0]+p0[1]) + (p0[2]+p0[3]))
                        + ((p1[0]+p1[1]) + (p1[2]+p1[3]));
                u16* prow = &Pw[(qs * 16 + fr) * 40];
                *(uint2*)&prow[fq * 4]      = make_uint2(pkbf(p0[0],p0[1]), pkbf(p0[2],p0[3]));
                *(uint2*)&prow[16 + fq * 4] = make_uint2(pkbf(p1[0],p1[1]), pkbf(p1[2],p1[3]));
            }
            // 3. QK for ci+1 (MFMA issue overlaps P-write latency)
            {
                f32x4 z; z[0] = z[1] = z[2] = z[3] = 0.f;
                #pragma unroll
                for (int qs = 0; qs < 2; qs++) {
                    st[np][0][qs] = __builtin_amdgcn_mfma_f32_16x16x32_bf16(kA[np], qf[qs], z, 0, 0, 0);
                    st[np][1][qs] = __builtin_amdgcn_mfma_f32_16x16x32_bf16(kB[np], qf[qs], z, 0, 0, 0);
                }
            }
            // 4. PV: O^T += V^T * P^T
            bf16x8 pf0 = *(const bf16x8*)&Pw[fr * 40 + fq * 8];
            bf16x8 pf1 = *(const bf16x8*)&Pw[(16 + fr) * 40 + fq * 8];
            bf16x8 vf0 = *(const bf16x8*)&Vt[kw][sub * 1296 + fr * 40 + fq * 8];
            bf16x8 vf1 = *(const bf16x8*)&Vt[kw][sub * 1296 + (16 + fr) * 40 + fq * 8];
            o[0][0] = __builtin_amdgcn_mfma_f32_16x16x32_bf16(vf0, pf0, o[0][0], 0, 0, 0);
            o[0][1] = __builtin_amdgcn_mfma_f32_16x16x32_bf16(vf0, pf1, o[0][1], 0, 0, 0);
            o[1][0] = __builtin_amdgcn_mfma_f32_16x16x32_bf16(vf1, pf0, o[1][0], 0, 0, 0);
            o[1][1] = __builtin_amdgcn_mfma_f32_16x16x32_bf16(vf1, pf1, o[1][1], 0, 0, 0);
        }
    }
    // reduce ps across fq within each wave
    #pragma unroll
    for (int qs = 0; qs < 2; qs++) {
        ps[qs] += __shfl_xor(ps[qs], 16, 64);
        ps[qs] += __shfl_xor(ps[qs], 32, 64);
    }
    // merge kv halves: kw=1 dumps (o, ps); kw=0 adds + stores
    __syncthreads();
    float* mrg = (float*)&Vt[0][0];   // 128 lanes x 18 floats = 9216 B
    if (kw == 1) {
        float* p = mrg + (qw * 64 + l) * 18;
        #pragma unroll
        for (int ds = 0; ds < 2; ds++)
            #pragma unroll
            for (int qs = 0; qs < 2; qs++)
                #pragma unroll
                for (int r = 0; r < 4; r++) p[ds * 8 + qs * 4 + r] = o[ds][qs][r];
        p[16] = ps[0]; p[17] = ps[1];
    }
    __syncthreads();
    if (kw == 0) {
        const float* p = mrg + (qw * 64 + l) * 18;
        #pragma unroll
        for (int ds = 0; ds < 2; ds++)
            #pragma unroll
            for (int qs = 0; qs < 2; qs++)
                #pragma unroll
                for (int r = 0; r < 4; r++) o[ds][qs][r] += p[ds * 8 + qs * 4 + r];
        ps[0] += p[16]; ps[1] += p[17];
        #pragma unroll
        for (int qs = 0; qs < 2; qs++) {
            float inv = 1.f / ps[qs];
            int tok = (int)btok + q0 + qw * 32 + qs * 16 + fr;
            #pragma unroll
            for (int ds = 0; ds < 2; ds++) {
                *(uint2*)(attn + (size_t)tok * 256 + h * 32 + ds * 16 + fq * 4) =
                    make_uint2(pkbf(o[ds][qs][0]*inv, o[ds][qs][1]*inv),
                               pkbf(o[ds][qs][2]*inv, o[ds][qs][3]*inv));
            }
        }
    }
#undef KLOAD
}

extern "C" void kernel_launch(void* const* d_in, const int* in_sizes, int n_in,
                              void* d_out, int out_size, void* d_ws, size_t ws_size,
                              hipStream_t stream) {
    const float* src  = (const float*)d_in[0];
    const float* w_in = (const float*)d_in[1];
    const float* w_out= (const float*)d_in[2];
    const float* w1   = (const float*)d_in[3];
    const float* b1   = (const float*)d_in[4];
    const float* w2   = (const float*)d_in[5];
    const float* b2   = (const float*)d_in[6];
    const float* g1   = (const float*)d_in[7];
    const float* be1  = (const float*)d_in[8];
    const float* g2   = (const float*)d_in[9];
    const float* be2  = (const float*)d_in[10];
    float* out = (float*)d_out;

    u16* xb    = (u16*)d_ws;                       // 8192*256
    u16* qkvb  = xb + (size_t)NTOK * 256;          // 8192*768
    u16* attnb = xb;                               // reuse (xb dead after G2)
    u16* h1b   = (u16*)d_ws;                       // 8192*1024 (after attn GEMMs)
    u16* x2b   = (u16*)((char*)d_ws + (size_t)NTOK * 1024 * 2);
    u16* wib   = x2b + (size_t)NTOK * 256;
    u16* wob   = wib + 768 * 256;
    u16* w1b   = wob + 256 * 256;
    u16* w2b   = w1b + 1024 * 256;

    convw<<<768, 256, 0, stream>>>(w_in, wib, w_out, wob, w1, w1b, w2, w2b);
    // 1. xb = LN1(src) -> bf16
    ln_bf<<<NTOK / 4, 256, 0, stream>>>(src, xb, g1, be1);
    // 2. qkvb = xb @ w_in^T (q cols scaled by QSCALE*log2e); 768 blocks = 3/CU
    wgemm<256, 64, 4, 0><<<dim3(12, 64), 256, 0, stream>>>(
        xb, wib, nullptr, nullptr, nullptr, qkvb, 768);
    // 3. attnb = flash-attention(qkvb)
    attn_k<<<dim3(32, 32), 256, 0, stream>>>(qkvb, attnb);
    // 4. out = src + attnb @ w_out^T (fp32); 512 blocks = 2/CU
    wgemm<256, 32, 2, 1><<<dim3(8, 64), 256, 0, stream>>>(
        attnb, wob, nullptr, src, out, nullptr, 256);
    // 5. x2b = LN2(out) -> bf16
    ln_bf<<<NTOK / 4, 256, 0, stream>>>(out, x2b, g2, be2);
    // 6. h1b = relu(x2b @ w1^T + b1) -> bf16; 1024 blocks = 4/CU
    wgemm<256, 64, 4, 2><<<dim3(16, 64), 256, 0, stream>>>(
        x2b, w1b, b1, nullptr, nullptr, h1b, 1024);
    // 7. out = out + h1b @ w2^T + b2 (in-place, 2-chunk W staging, no atomics)
    wgemm<1024, 32, 2, 3><<<dim3(8, 64), 256, 0, stream>>>(
        h1b, w2b, b2, nullptr, out, nullptr, 256);
}